// Round 1
// baseline (1059.241 us; speedup 1.0000x reference)
//
#include <hip/hip_runtime.h>

#define DEV __device__ __forceinline__

namespace {

constexpr int B_ = 8;
constexpr int N_ = 1024;
constexpr int M_ = 256;
constexpr int D_ = 25;
constexpr int FH_ = 240;
constexpr int NATOM = B_ * N_;          // 8192
constexpr float CSC = 1.0f / 256.0f;    // 4/(NN*NTYPES*4)

DEV float fast_tanh(float x) {
  float ax = fabsf(x);
  float e = __expf(-2.0f * ax);
  float r = (1.0f - e) * __builtin_amdgcn_rcpf(1.0f + e);
  return copysignf(r, x);
}

// Geometry: smooth-cutoff descriptor channels blk[4] (normalized) and
// optionally the 4x3 Jacobian rid[12] (normalized), per (atom, neighbor).
template <bool WANT_RID>
DEV void compute_geom(float dx, float dy, float dz, int nb, int t, int m,
                      const float* __restrict__ davg, const float* __restrict__ dstd,
                      float* __restrict__ blk, float* __restrict__ rid) {
  float mf = (nb > 0) ? 1.0f : 0.0f;
  float dr2 = dx * dx + dy * dy + dz * dz;
  float safe = (nb > 0) ? dr2 : 1.0f;
  float rij = sqrtf(safe);
  float inr = mf / rij;
  float x = rij * mf;
  float inr2 = inr * inr;
  float inr4 = inr2 * inr2;
  float inr3 = inr4 * x;
  float u = (x - 5.8f) * 5.0f;                 // (x-RMIN)/(RMAX-RMIN)
  float uu = u * u;
  float A = -6.0f * uu + 15.0f * u - 10.0f;
  float poly = uu * u * A + 1.0f;
  float dpoly = (3.0f * uu * A + uu * u * (-12.0f * u + 15.0f)) * 5.0f;
  bool mid = (x >= 5.8f) && (x < 6.0f);
  float vv = ((x < 5.8f) ? 1.0f : (mid ? poly : 0.0f)) * mf;
  float dvv = (mid ? dpoly : 0.0f) * mf;
  float pre[4];
  pre[0] = inr;
  pre[1] = dx * inr2;
  pre[2] = dy * inr2;
  pre[3] = dz * inr2;
  int bidx = (t * M_ + m) * 4;
  float4 av = *(const float4*)(davg + bidx);
  float4 sv = *(const float4*)(dstd + bidx);
  float avf[4] = {av.x, av.y, av.z, av.w};
  float svf[4] = {sv.x, sv.y, sv.z, sv.w};
#pragma unroll
  for (int d = 0; d < 4; ++d) blk[d] = (pre[d] * vv - avf[d]) / svf[d];
  if (WANT_RID) {
    float dv[3] = {dx, dy, dz};
    float ci = dvv * inr;
    float com[3];
#pragma unroll
    for (int c = 0; c < 3; ++c) com[c] = ci * dv[c];
    float iv = inr3 * vv;
#pragma unroll
    for (int c = 0; c < 3; ++c)
      rid[c] = (dv[c] * iv - pre[0] * com[c]) * mf / svf[0];
#pragma unroll
    for (int r = 0; r < 3; ++r) {
#pragma unroll
      for (int c = 0; c < 3; ++c) {
        float outer = 2.0f * dv[r] * dv[c] * inr4 - ((r == c) ? inr2 : 0.0f);
        rid[(1 + r) * 3 + c] = (outer * vv - pre[1 + r] * com[c]) * mf / svf[1 + r];
      }
    }
  }
}

// Embedding MLP forward. Weights are wave-uniform pointers -> SGPR loads.
DEV void embed_fwd(float s, const float* __restrict__ W0, const float* __restrict__ b0,
                   const float* __restrict__ W1, const float* __restrict__ b1,
                   const float* __restrict__ W2, const float* __restrict__ b2,
                   float* __restrict__ h0, float* __restrict__ t1v,
                   float* __restrict__ h1, float* __restrict__ t2v) {
#pragma unroll
  for (int e = 0; e < D_; ++e) h0[e] = fast_tanh(fmaf(s, W0[e], b0[e]));
  float a[D_];
#pragma unroll
  for (int e = 0; e < D_; ++e) a[e] = b1[e];
#pragma unroll
  for (int f = 0; f < D_; ++f) {
    float hf = h0[f];
#pragma unroll
    for (int e = 0; e < D_; ++e) a[e] = fmaf(hf, W1[f * D_ + e], a[e]);
  }
#pragma unroll
  for (int e = 0; e < D_; ++e) { t1v[e] = fast_tanh(a[e]); h1[e] = h0[e] + t1v[e]; }
#pragma unroll
  for (int e = 0; e < D_; ++e) a[e] = b2[e];
#pragma unroll
  for (int f = 0; f < D_; ++f) {
    float hf = h1[f];
#pragma unroll
    for (int e = 0; e < D_; ++e) a[e] = fmaf(hf, W2[f * D_ + e], a[e]);
  }
#pragma unroll
  for (int e = 0; e < D_; ++e) t2v[e] = fast_tanh(a[e]);
}

// K1: per atom (block), per neighbor (thread): geometry + embedding fwd,
// then acc[4][25] = CSC * sum_m blk[m][d] * G[m][e] via LDS reduction.
__global__ __launch_bounds__(256) void k_embed_acc(
    const float* __restrict__ dR, const int* __restrict__ neigh,
    const float* __restrict__ davg, const float* __restrict__ dstd,
    const float* __restrict__ eW0, const float* __restrict__ eb0,
    const float* __restrict__ eW1, const float* __restrict__ eb1,
    const float* __restrict__ eW2, const float* __restrict__ eb2,
    float* __restrict__ acc_ws) {
  __shared__ float sG[M_ * D_];
  __shared__ float4 sBlk[M_];
  int atom = blockIdx.x;
  int n = atom & (N_ - 1);
  int t = (n >= 512) ? 1 : 0;
  int m = threadIdx.x;
  // pair index is uniform across each 64-lane wave (m>>7 constant per wave)
  int p = __builtin_amdgcn_readfirstlane(t * 2 + (m >> 7));
  const float* W0 = eW0 + p * D_;
  const float* b0 = eb0 + p * D_;
  const float* W1 = eW1 + p * D_ * D_;
  const float* b1 = eb1 + p * D_;
  const float* W2 = eW2 + p * D_ * D_;
  const float* b2 = eb2 + p * D_;
  int base = atom * M_ + m;
  float dx = dR[base * 3 + 0];
  float dy = dR[base * 3 + 1];
  float dz = dR[base * 3 + 2];
  int nb = neigh[base];
  float blk[4];
  compute_geom<false>(dx, dy, dz, nb, t, m, davg, dstd, blk, nullptr);
  float h0[D_], t1v[D_], h1[D_], t2v[D_];
  embed_fwd(blk[0], W0, b0, W1, b1, W2, b2, h0, t1v, h1, t2v);
#pragma unroll
  for (int e = 0; e < D_; ++e) sG[m * D_ + e] = h1[e] + t2v[e];
  sBlk[m] = make_float4(blk[0], blk[1], blk[2], blk[3]);
  __syncthreads();
  if (threadIdx.x < 100) {
    int d = threadIdx.x & 3;
    int e = threadIdx.x >> 2;
    const float* sb = (const float*)sBlk;
    float sum = 0.0f;
    for (int mm = 0; mm < M_; ++mm)
      sum = fmaf(sb[mm * 4 + d], sG[mm * D_ + e], sum);
    acc_ws[atom * 100 + d * D_ + e] = sum * CSC;
  }
}

// K2: 8 atoms per block. DRt + fitting net fwd + bwd, emits Ei/Etot and dacc.
__global__ __launch_bounds__(256) void k_fit(
    const float* __restrict__ acc_ws,
    const float* __restrict__ fW0, const float* __restrict__ fb0,
    const float* __restrict__ fW1, const float* __restrict__ fb1,
    const float* __restrict__ fW2, const float* __restrict__ fb2,
    const float* __restrict__ fW3, const float* __restrict__ fb3,
    const float* __restrict__ ener_shift,
    float* __restrict__ dacc_ws, float* __restrict__ out) {
  constexpr int AB = 8;
  __shared__ float sAcc[AB][100];
  __shared__ float sX[AB][400];   // x fwd, then dx bwd
  __shared__ float sH0[AB][FH_];  // h0, then g0
  __shared__ float sT1[AB][FH_];  // tanh1, then g1
  __shared__ float sH1[AB][FH_];  // h1, then dh1
  __shared__ float sT2[AB][FH_];  // tanh2, then g2
  __shared__ float sEi[AB];
  int a0 = blockIdx.x * AB;
  int bb = a0 >> 10;
  int n0 = a0 & (N_ - 1);
  int t = (n0 >= 512) ? 1 : 0;
  int tid = threadIdx.x;
  for (int idx = tid; idx < AB * 100; idx += 256)
    ((float*)sAcc)[idx] = acc_ws[a0 * 100 + idx];
  if (tid < AB) sEi[tid] = 0.0f;
  __syncthreads();
  // DRt[e][f] = sum_d acc[d][e]*acc[d][f], f<16
  for (int idx = tid; idx < AB * 400; idx += 256) {
    int a = idx / 400; int r = idx % 400; int e = r >> 4; int f = r & 15;
    const float* A = sAcc[a];
    sX[a][r] = A[e] * A[f] + A[25 + e] * A[25 + f] + A[50 + e] * A[50 + f] +
               A[75 + e] * A[75 + f];
  }
  __syncthreads();
  const float* W0 = fW0 + t * 400 * FH_;
  const float* W1 = fW1 + t * FH_ * FH_;
  const float* W2 = fW2 + t * FH_ * FH_;
  const float* B0 = fb0 + t * FH_;
  const float* B1 = fb1 + t * FH_;
  const float* B2 = fb2 + t * FH_;
  const float* W3 = fW3 + t * FH_;
  int j = tid;
  if (j < FH_) {  // layer 0: 400 -> 240
    float acc8[AB];
#pragma unroll
    for (int a = 0; a < AB; ++a) acc8[a] = B0[j];
    for (int i = 0; i < 400; ++i) {
      float w = W0[i * FH_ + j];
#pragma unroll
      for (int a = 0; a < AB; ++a) acc8[a] = fmaf(sX[a][i], w, acc8[a]);
    }
#pragma unroll
    for (int a = 0; a < AB; ++a) sH0[a][j] = fast_tanh(acc8[a]);
  }
  __syncthreads();
  if (j < FH_) {  // layer 1 (residual)
    float acc8[AB];
#pragma unroll
    for (int a = 0; a < AB; ++a) acc8[a] = B1[j];
    for (int f = 0; f < FH_; ++f) {
      float w = W1[f * FH_ + j];
#pragma unroll
      for (int a = 0; a < AB; ++a) acc8[a] = fmaf(sH0[a][f], w, acc8[a]);
    }
#pragma unroll
    for (int a = 0; a < AB; ++a) {
      float tv = fast_tanh(acc8[a]);
      sT1[a][j] = tv;
      sH1[a][j] = sH0[a][j] + tv;
    }
  }
  __syncthreads();
  if (j < FH_) {  // layer 2 (residual) + Ei dot
    float acc8[AB];
#pragma unroll
    for (int a = 0; a < AB; ++a) acc8[a] = B2[j];
    for (int f = 0; f < FH_; ++f) {
      float w = W2[f * FH_ + j];
#pragma unroll
      for (int a = 0; a < AB; ++a) acc8[a] = fmaf(sH1[a][f], w, acc8[a]);
    }
    float w3 = W3[j];
#pragma unroll
    for (int a = 0; a < AB; ++a) {
      float tv = fast_tanh(acc8[a]);
      sT2[a][j] = tv;
      atomicAdd(&sEi[a], (sH1[a][j] + tv) * w3);
    }
  }
  __syncthreads();
  if (tid < AB) {
    float ei = sEi[tid] + fb3[t] + ener_shift[t];
    out[8 + a0 + tid] = ei;            // Ei
    atomicAdd(&out[bb], ei);           // Etot
  }
  if (j < FH_) {  // g2 = W3 * (1 - t2^2)   (dEi = 1)
    float w3 = W3[j];
#pragma unroll
    for (int a = 0; a < AB; ++a) {
      float tv = sT2[a][j];
      sT2[a][j] = w3 * (1.0f - tv * tv);
    }
  }
  __syncthreads();
  if (j < FH_) {  // dh1 = W3 + g2 @ W2^T ; g1 = dh1*(1-t1^2)
    float w3 = W3[j];
    float acc8[AB];
#pragma unroll
    for (int a = 0; a < AB; ++a) acc8[a] = w3;
    for (int k = 0; k < FH_; ++k) {
      float w = W2[j * FH_ + k];
#pragma unroll
      for (int a = 0; a < AB; ++a) acc8[a] = fmaf(sT2[a][k], w, acc8[a]);
    }
#pragma unroll
    for (int a = 0; a < AB; ++a) {
      float dh1 = acc8[a];
      float tv = sT1[a][j];
      sH1[a][j] = dh1;
      sT1[a][j] = dh1 * (1.0f - tv * tv);
    }
  }
  __syncthreads();
  if (j < FH_) {  // dh0 = dh1 + g1 @ W1^T ; g0 = dh0*(1-h0^2)
    float acc8[AB];
#pragma unroll
    for (int a = 0; a < AB; ++a) acc8[a] = sH1[a][j];
    for (int k = 0; k < FH_; ++k) {
      float w = W1[j * FH_ + k];
#pragma unroll
      for (int a = 0; a < AB; ++a) acc8[a] = fmaf(sT1[a][k], w, acc8[a]);
    }
#pragma unroll
    for (int a = 0; a < AB; ++a) {
      float h0v = sH0[a][j];
      sH0[a][j] = acc8[a] * (1.0f - h0v * h0v);
    }
  }
  __syncthreads();
  // dx = g0 @ W0^T  (overwrite sX)
  for (int i = tid; i < 400; i += 256) {
    float acc8[AB];
#pragma unroll
    for (int a = 0; a < AB; ++a) acc8[a] = 0.0f;
    for (int jj = 0; jj < FH_; ++jj) {
      float w = W0[i * FH_ + jj];
#pragma unroll
      for (int a = 0; a < AB; ++a) acc8[a] = fmaf(sH0[a][jj], w, acc8[a]);
    }
#pragma unroll
    for (int a = 0; a < AB; ++a) sX[a][i] = acc8[a];
  }
  __syncthreads();
  // dacc[d][e] = sum_{f<16} dDRt[e][f]*acc[d][f] + [e<16] sum_e2 dDRt[e2][e]*acc[d][e2]
  for (int idx = tid; idx < AB * 100; idx += 256) {
    int a = idx / 100; int r = idx % 100; int d = r / 25; int e = r % 25;
    const float* A = sAcc[a];
    const float* DX = sX[a];
    float sum = 0.0f;
#pragma unroll
    for (int f = 0; f < 16; ++f) sum = fmaf(DX[e * 16 + f], A[d * 25 + f], sum);
    if (e < 16) {
#pragma unroll
      for (int e2 = 0; e2 < 25; ++e2) sum = fmaf(DX[e2 * 16 + e], A[d * 25 + e2], sum);
    }
    dacc_ws[a0 * 100 + idx] = sum;
  }
}

// K3: per atom (block), per neighbor (thread): recompute geometry + embedding,
// embedding VJP -> dE -> pair -> F_self (LDS reduce) + scatter atomics.
__global__ __launch_bounds__(256) void k_bwd_force(
    const float* __restrict__ dR, const int* __restrict__ neigh,
    const float* __restrict__ davg, const float* __restrict__ dstd,
    const float* __restrict__ eW0, const float* __restrict__ eb0,
    const float* __restrict__ eW1, const float* __restrict__ eb1,
    const float* __restrict__ eW2, const float* __restrict__ eb2,
    const float* __restrict__ dacc_ws, float* __restrict__ out) {
  __shared__ float sF[3];
  int atom = blockIdx.x;
  int bb = atom >> 10;
  int n = atom & (N_ - 1);
  int t = (n >= 512) ? 1 : 0;
  int m = threadIdx.x;
  if (m < 3) sF[m] = 0.0f;
  __syncthreads();
  int p = __builtin_amdgcn_readfirstlane(t * 2 + (m >> 7));
  const float* W0 = eW0 + p * D_;
  const float* b0 = eb0 + p * D_;
  const float* W1 = eW1 + p * D_ * D_;
  const float* b1 = eb1 + p * D_;
  const float* W2 = eW2 + p * D_ * D_;
  const float* b2 = eb2 + p * D_;
  const float* dac = dacc_ws + atom * 100;  // block-uniform -> scalar loads
  int base = atom * M_ + m;
  float dx = dR[base * 3 + 0];
  float dy = dR[base * 3 + 1];
  float dz = dR[base * 3 + 2];
  int nb = neigh[base];
  float blk[4], rid[12];
  compute_geom<true>(dx, dy, dz, nb, t, m, davg, dstd, blk, rid);
  float h0[D_], t1v[D_], h1[D_], t2v[D_];
  embed_fwd(blk[0], W0, b0, W1, b1, W2, b2, h0, t1v, h1, t2v);
  // dblk[d] = CSC * sum_e dacc[d][e] * G[e]
  float dblk[4];
#pragma unroll
  for (int d = 0; d < 4; ++d) {
    float s = 0.0f;
#pragma unroll
    for (int e = 0; e < D_; ++e) s = fmaf(dac[d * D_ + e], h1[e] + t2v[e], s);
    dblk[d] = s * CSC;
  }
  // dG[e] = CSC * sum_d dacc[d][e] * blk[d]
  float dG[D_];
#pragma unroll
  for (int e = 0; e < D_; ++e)
    dG[e] = CSC * (dac[e] * blk[0] + dac[25 + e] * blk[1] +
                   dac[50 + e] * blk[2] + dac[75 + e] * blk[3]);
  // embedding VJP
  float g[D_];
#pragma unroll
  for (int e = 0; e < D_; ++e) g[e] = dG[e] * (1.0f - t2v[e] * t2v[e]);  // g2
#pragma unroll
  for (int e = 0; e < D_; ++e) {  // dh1 = dG + g2 @ W2^T (in place)
    float s = dG[e];
#pragma unroll
    for (int f = 0; f < D_; ++f) s = fmaf(g[f], W2[e * D_ + f], s);
    dG[e] = s;
  }
#pragma unroll
  for (int e = 0; e < D_; ++e) g[e] = dG[e] * (1.0f - t1v[e] * t1v[e]);  // g1
#pragma unroll
  for (int e = 0; e < D_; ++e) {  // dh0 = dh1 + g1 @ W1^T (in place)
    float s = dG[e];
#pragma unroll
    for (int f = 0; f < D_; ++f) s = fmaf(g[f], W1[e * D_ + f], s);
    dG[e] = s;
  }
  float ds = 0.0f;
#pragma unroll
  for (int e = 0; e < D_; ++e) ds = fmaf(dG[e] * (1.0f - h0[e] * h0[e]), W0[e], ds);
  float dE0 = dblk[0] + ds, dE1 = dblk[1], dE2 = dblk[2], dE3 = dblk[3];
  float px = dE0 * rid[0] + dE1 * rid[3] + dE2 * rid[6] + dE3 * rid[9];
  float py = dE0 * rid[1] + dE1 * rid[4] + dE2 * rid[7] + dE3 * rid[10];
  float pz = dE0 * rid[2] + dE1 * rid[5] + dE2 * rid[8] + dE3 * rid[11];
  atomicAdd(&sF[0], px);
  atomicAdd(&sF[1], py);
  atomicAdd(&sF[2], pz);
  if (nb > 0) {  // scatter to neighbor j = nb-1
    int jn = nb - 1;
    int fi = 8 + NATOM + (bb * N_ + jn) * 3;
    atomicAdd(&out[fi + 0], px);
    atomicAdd(&out[fi + 1], py);
    atomicAdd(&out[fi + 2], pz);
  }
  __syncthreads();
  if (m < 3) atomicAdd(&out[8 + NATOM + atom * 3 + m], -sF[m]);
}

}  // namespace

extern "C" void kernel_launch(void* const* d_in, const int* in_sizes, int n_in,
                              void* d_out, int out_size, void* d_ws, size_t ws_size,
                              hipStream_t stream) {
  (void)in_sizes; (void)n_in; (void)ws_size;
  const float* image_dR   = (const float*)d_in[0];
  const int*   list_neigh = (const int*)d_in[1];
  const float* davg       = (const float*)d_in[2];
  const float* dstd       = (const float*)d_in[3];
  const float* eW0        = (const float*)d_in[4];
  const float* eb0        = (const float*)d_in[5];
  const float* eW1        = (const float*)d_in[6];
  const float* eb1        = (const float*)d_in[7];
  const float* eW2        = (const float*)d_in[8];
  const float* eb2        = (const float*)d_in[9];
  const float* fW0        = (const float*)d_in[10];
  const float* fb0        = (const float*)d_in[11];
  const float* fW1        = (const float*)d_in[12];
  const float* fb1        = (const float*)d_in[13];
  const float* fW2        = (const float*)d_in[14];
  const float* fb2        = (const float*)d_in[15];
  const float* fW3        = (const float*)d_in[16];
  const float* fb3        = (const float*)d_in[17];
  const float* ener_shift = (const float*)d_in[18];
  float* out = (float*)d_out;
  float* acc_ws  = (float*)d_ws;                  // 8192*100 floats
  float* dacc_ws = acc_ws + NATOM * 100;          // 8192*100 floats

  hipMemsetAsync(d_out, 0, (size_t)out_size * sizeof(float), stream);
  k_embed_acc<<<NATOM, 256, 0, stream>>>(image_dR, list_neigh, davg, dstd,
                                         eW0, eb0, eW1, eb1, eW2, eb2, acc_ws);
  k_fit<<<NATOM / 8, 256, 0, stream>>>(acc_ws, fW0, fb0, fW1, fb1, fW2, fb2,
                                       fW3, fb3, ener_shift, dacc_ws, out);
  k_bwd_force<<<NATOM, 256, 0, stream>>>(image_dR, list_neigh, davg, dstd,
                                         eW0, eb0, eW1, eb1, eW2, eb2,
                                         dacc_ws, out);
}

// Round 2
// 1053.504 us; speedup vs baseline: 1.0054x; 1.0054x over previous
//
#include <hip/hip_runtime.h>

#define DEV __device__ __forceinline__

namespace {

constexpr int B_ = 8;
constexpr int N_ = 1024;
constexpr int M_ = 256;
constexpr int D_ = 25;
constexpr int FH_ = 240;
constexpr int NATOM = B_ * N_;          // 8192
constexpr float CSC = 1.0f / 256.0f;    // 4/(NN*NTYPES*4)

DEV float fast_tanh(float x) {
  float ax = fabsf(x);
  float e = __expf(-2.0f * ax);
  float r = (1.0f - e) * __builtin_amdgcn_rcpf(1.0f + e);
  return copysignf(r, x);
}

// Geometry: smooth-cutoff descriptor channels blk[4] (normalized) and
// optionally the 4x3 Jacobian rid[12] (normalized), per (atom, neighbor).
// Uses v_rsq / v_rcp instead of IEEE div/sqrt expansions (quarter-rate
// single instructions; absmax budget is generous).
template <bool WANT_RID>
DEV void compute_geom(float dx, float dy, float dz, int nb, int t, int m,
                      const float* __restrict__ davg, const float* __restrict__ dstd,
                      float* __restrict__ blk, float* __restrict__ rid) {
  float mf = (nb > 0) ? 1.0f : 0.0f;
  float dr2 = dx * dx + dy * dy + dz * dz;
  float safe = (nb > 0) ? dr2 : 1.0f;
  float rs = __builtin_amdgcn_rsqf(safe);   // 1/sqrt(safe)
  float rij = safe * rs;                    // sqrt(safe)
  float inr = mf * rs;
  float x = rij * mf;
  float inr2 = inr * inr;
  float inr4 = inr2 * inr2;
  float inr3 = inr4 * x;
  float u = (x - 5.8f) * 5.0f;                 // (x-RMIN)/(RMAX-RMIN)
  float uu = u * u;
  float A = -6.0f * uu + 15.0f * u - 10.0f;
  float poly = uu * u * A + 1.0f;
  float dpoly = (3.0f * uu * A + uu * u * (-12.0f * u + 15.0f)) * 5.0f;
  bool mid = (x >= 5.8f) && (x < 6.0f);
  float vv = ((x < 5.8f) ? 1.0f : (mid ? poly : 0.0f)) * mf;
  float dvv = (mid ? dpoly : 0.0f) * mf;
  float pre[4];
  pre[0] = inr;
  pre[1] = dx * inr2;
  pre[2] = dy * inr2;
  pre[3] = dz * inr2;
  int bidx = (t * M_ + m) * 4;
  float4 av = *(const float4*)(davg + bidx);
  float4 sv = *(const float4*)(dstd + bidx);
  float avf[4] = {av.x, av.y, av.z, av.w};
  float rsv[4] = {__builtin_amdgcn_rcpf(sv.x), __builtin_amdgcn_rcpf(sv.y),
                  __builtin_amdgcn_rcpf(sv.z), __builtin_amdgcn_rcpf(sv.w)};
#pragma unroll
  for (int d = 0; d < 4; ++d) blk[d] = (pre[d] * vv - avf[d]) * rsv[d];
  if (WANT_RID) {
    float dv[3] = {dx, dy, dz};
    float ci = dvv * inr;
    float com[3];
#pragma unroll
    for (int c = 0; c < 3; ++c) com[c] = ci * dv[c];
    float iv = inr3 * vv;
#pragma unroll
    for (int c = 0; c < 3; ++c)
      rid[c] = (dv[c] * iv - pre[0] * com[c]) * mf * rsv[0];
#pragma unroll
    for (int r = 0; r < 3; ++r) {
#pragma unroll
      for (int c = 0; c < 3; ++c) {
        float outer = 2.0f * dv[r] * dv[c] * inr4 - ((r == c) ? inr2 : 0.0f);
        rid[(1 + r) * 3 + c] = (outer * vv - pre[1 + r] * com[c]) * mf * rsv[1 + r];
      }
    }
  }
}

// Embedding MLP forward. Weights are wave-uniform pointers -> SGPR loads.
DEV void embed_fwd(float s, const float* __restrict__ W0, const float* __restrict__ b0,
                   const float* __restrict__ W1, const float* __restrict__ b1,
                   const float* __restrict__ W2, const float* __restrict__ b2,
                   float* __restrict__ h0, float* __restrict__ t1v,
                   float* __restrict__ h1, float* __restrict__ t2v) {
#pragma unroll
  for (int e = 0; e < D_; ++e) h0[e] = fast_tanh(fmaf(s, W0[e], b0[e]));
  float a[D_];
#pragma unroll
  for (int e = 0; e < D_; ++e) a[e] = b1[e];
#pragma unroll
  for (int f = 0; f < D_; ++f) {
    float hf = h0[f];
#pragma unroll
    for (int e = 0; e < D_; ++e) a[e] = fmaf(hf, W1[f * D_ + e], a[e]);
  }
#pragma unroll
  for (int e = 0; e < D_; ++e) { t1v[e] = fast_tanh(a[e]); h1[e] = h0[e] + t1v[e]; }
#pragma unroll
  for (int e = 0; e < D_; ++e) a[e] = b2[e];
#pragma unroll
  for (int f = 0; f < D_; ++f) {
    float hf = h1[f];
#pragma unroll
    for (int e = 0; e < D_; ++e) a[e] = fmaf(hf, W2[f * D_ + e], a[e]);
  }
#pragma unroll
  for (int e = 0; e < D_; ++e) t2v[e] = fast_tanh(a[e]);
}

// K1: per atom (block), per neighbor (thread): geometry + embedding fwd,
// then acc[4][25] = CSC * sum_m blk[m][d] * G[m][e] via LDS reduction.
// launch_bounds(256,2): VGPR cap 256 — ~110 live floats, must not spill.
__global__ __launch_bounds__(256, 2) void k_embed_acc(
    const float* __restrict__ dR, const int* __restrict__ neigh,
    const float* __restrict__ davg, const float* __restrict__ dstd,
    const float* __restrict__ eW0, const float* __restrict__ eb0,
    const float* __restrict__ eW1, const float* __restrict__ eb1,
    const float* __restrict__ eW2, const float* __restrict__ eb2,
    float* __restrict__ acc_ws) {
  __shared__ float sG[M_ * D_];
  __shared__ float4 sBlk[M_];
  int atom = blockIdx.x;
  int n = atom & (N_ - 1);
  int t = (n >= 512) ? 1 : 0;
  int m = threadIdx.x;
  // pair index is uniform across each 64-lane wave (m>>7 constant per wave)
  int p = __builtin_amdgcn_readfirstlane(t * 2 + (m >> 7));
  const float* W0 = eW0 + p * D_;
  const float* b0 = eb0 + p * D_;
  const float* W1 = eW1 + p * D_ * D_;
  const float* b1 = eb1 + p * D_;
  const float* W2 = eW2 + p * D_ * D_;
  const float* b2 = eb2 + p * D_;
  int base = atom * M_ + m;
  float dx = dR[base * 3 + 0];
  float dy = dR[base * 3 + 1];
  float dz = dR[base * 3 + 2];
  int nb = neigh[base];
  float blk[4];
  compute_geom<false>(dx, dy, dz, nb, t, m, davg, dstd, blk, nullptr);
  float h0[D_], t1v[D_], h1[D_], t2v[D_];
  embed_fwd(blk[0], W0, b0, W1, b1, W2, b2, h0, t1v, h1, t2v);
#pragma unroll
  for (int e = 0; e < D_; ++e) sG[m * D_ + e] = h1[e] + t2v[e];
  sBlk[m] = make_float4(blk[0], blk[1], blk[2], blk[3]);
  __syncthreads();
  if (threadIdx.x < 100) {
    int d = threadIdx.x & 3;
    int e = threadIdx.x >> 2;
    const float* sb = (const float*)sBlk;
    float sum = 0.0f;
    for (int mm = 0; mm < M_; ++mm)
      sum = fmaf(sb[mm * 4 + d], sG[mm * D_ + e], sum);
    acc_ws[atom * 100 + d * D_ + e] = sum * CSC;
  }
}

// K2: 8 atoms per block. DRt + fitting net fwd + bwd, emits Ei/Etot and dacc.
__global__ __launch_bounds__(256) void k_fit(
    const float* __restrict__ acc_ws,
    const float* __restrict__ fW0, const float* __restrict__ fb0,
    const float* __restrict__ fW1, const float* __restrict__ fb1,
    const float* __restrict__ fW2, const float* __restrict__ fb2,
    const float* __restrict__ fW3, const float* __restrict__ fb3,
    const float* __restrict__ ener_shift,
    float* __restrict__ dacc_ws, float* __restrict__ out) {
  constexpr int AB = 8;
  __shared__ float sAcc[AB][100];
  __shared__ float sX[AB][400];   // x fwd, then dx bwd
  __shared__ float sH0[AB][FH_];  // h0, then g0
  __shared__ float sT1[AB][FH_];  // tanh1, then g1
  __shared__ float sH1[AB][FH_];  // h1, then dh1
  __shared__ float sT2[AB][FH_];  // tanh2, then g2
  __shared__ float sEi[AB];
  int a0 = blockIdx.x * AB;
  int bb = a0 >> 10;
  int n0 = a0 & (N_ - 1);
  int t = (n0 >= 512) ? 1 : 0;
  int tid = threadIdx.x;
  for (int idx = tid; idx < AB * 100; idx += 256)
    ((float*)sAcc)[idx] = acc_ws[a0 * 100 + idx];
  if (tid < AB) sEi[tid] = 0.0f;
  __syncthreads();
  // DRt[e][f] = sum_d acc[d][e]*acc[d][f], f<16
  for (int idx = tid; idx < AB * 400; idx += 256) {
    int a = idx / 400; int r = idx % 400; int e = r >> 4; int f = r & 15;
    const float* A = sAcc[a];
    sX[a][r] = A[e] * A[f] + A[25 + e] * A[25 + f] + A[50 + e] * A[50 + f] +
               A[75 + e] * A[75 + f];
  }
  __syncthreads();
  const float* W0 = fW0 + t * 400 * FH_;
  const float* W1 = fW1 + t * FH_ * FH_;
  const float* W2 = fW2 + t * FH_ * FH_;
  const float* B0 = fb0 + t * FH_;
  const float* B1 = fb1 + t * FH_;
  const float* B2 = fb2 + t * FH_;
  const float* W3 = fW3 + t * FH_;
  int j = tid;
  if (j < FH_) {  // layer 0: 400 -> 240
    float acc8[AB];
#pragma unroll
    for (int a = 0; a < AB; ++a) acc8[a] = B0[j];
    for (int i = 0; i < 400; ++i) {
      float w = W0[i * FH_ + j];
#pragma unroll
      for (int a = 0; a < AB; ++a) acc8[a] = fmaf(sX[a][i], w, acc8[a]);
    }
#pragma unroll
    for (int a = 0; a < AB; ++a) sH0[a][j] = fast_tanh(acc8[a]);
  }
  __syncthreads();
  if (j < FH_) {  // layer 1 (residual)
    float acc8[AB];
#pragma unroll
    for (int a = 0; a < AB; ++a) acc8[a] = B1[j];
    for (int f = 0; f < FH_; ++f) {
      float w = W1[f * FH_ + j];
#pragma unroll
      for (int a = 0; a < AB; ++a) acc8[a] = fmaf(sH0[a][f], w, acc8[a]);
    }
#pragma unroll
    for (int a = 0; a < AB; ++a) {
      float tv = fast_tanh(acc8[a]);
      sT1[a][j] = tv;
      sH1[a][j] = sH0[a][j] + tv;
    }
  }
  __syncthreads();
  if (j < FH_) {  // layer 2 (residual) + Ei dot
    float acc8[AB];
#pragma unroll
    for (int a = 0; a < AB; ++a) acc8[a] = B2[j];
    for (int f = 0; f < FH_; ++f) {
      float w = W2[f * FH_ + j];
#pragma unroll
      for (int a = 0; a < AB; ++a) acc8[a] = fmaf(sH1[a][f], w, acc8[a]);
    }
    float w3 = W3[j];
#pragma unroll
    for (int a = 0; a < AB; ++a) {
      float tv = fast_tanh(acc8[a]);
      sT2[a][j] = tv;
      atomicAdd(&sEi[a], (sH1[a][j] + tv) * w3);
    }
  }
  __syncthreads();
  if (tid < AB) {
    float ei = sEi[tid] + fb3[t] + ener_shift[t];
    out[8 + a0 + tid] = ei;            // Ei
    atomicAdd(&out[bb], ei);           // Etot
  }
  if (j < FH_) {  // g2 = W3 * (1 - t2^2)   (dEi = 1)
    float w3 = W3[j];
#pragma unroll
    for (int a = 0; a < AB; ++a) {
      float tv = sT2[a][j];
      sT2[a][j] = w3 * (1.0f - tv * tv);
    }
  }
  __syncthreads();
  if (j < FH_) {  // dh1 = W3 + g2 @ W2^T ; g1 = dh1*(1-t1^2)
    float w3 = W3[j];
    float acc8[AB];
#pragma unroll
    for (int a = 0; a < AB; ++a) acc8[a] = w3;
    for (int k = 0; k < FH_; ++k) {
      float w = W2[j * FH_ + k];
#pragma unroll
      for (int a = 0; a < AB; ++a) acc8[a] = fmaf(sT2[a][k], w, acc8[a]);
    }
#pragma unroll
    for (int a = 0; a < AB; ++a) {
      float dh1 = acc8[a];
      float tv = sT1[a][j];
      sH1[a][j] = dh1;
      sT1[a][j] = dh1 * (1.0f - tv * tv);
    }
  }
  __syncthreads();
  if (j < FH_) {  // dh0 = dh1 + g1 @ W1^T ; g0 = dh0*(1-h0^2)
    float acc8[AB];
#pragma unroll
    for (int a = 0; a < AB; ++a) acc8[a] = sH1[a][j];
    for (int k = 0; k < FH_; ++k) {
      float w = W1[j * FH_ + k];
#pragma unroll
      for (int a = 0; a < AB; ++a) acc8[a] = fmaf(sT1[a][k], w, acc8[a]);
    }
#pragma unroll
    for (int a = 0; a < AB; ++a) {
      float h0v = sH0[a][j];
      sH0[a][j] = acc8[a] * (1.0f - h0v * h0v);
    }
  }
  __syncthreads();
  // dx = g0 @ W0^T  (overwrite sX)
  for (int i = tid; i < 400; i += 256) {
    float acc8[AB];
#pragma unroll
    for (int a = 0; a < AB; ++a) acc8[a] = 0.0f;
    for (int jj = 0; jj < FH_; ++jj) {
      float w = W0[i * FH_ + jj];
#pragma unroll
      for (int a = 0; a < AB; ++a) acc8[a] = fmaf(sH0[a][jj], w, acc8[a]);
    }
#pragma unroll
    for (int a = 0; a < AB; ++a) sX[a][i] = acc8[a];
  }
  __syncthreads();
  // dacc[d][e] = sum_{f<16} dDRt[e][f]*acc[d][f] + [e<16] sum_e2 dDRt[e2][e]*acc[d][e2]
  for (int idx = tid; idx < AB * 100; idx += 256) {
    int a = idx / 100; int r = idx % 100; int d = r / 25; int e = r % 25;
    const float* A = sAcc[a];
    const float* DX = sX[a];
    float sum = 0.0f;
#pragma unroll
    for (int f = 0; f < 16; ++f) sum = fmaf(DX[e * 16 + f], A[d * 25 + f], sum);
    if (e < 16) {
#pragma unroll
      for (int e2 = 0; e2 < 25; ++e2) sum = fmaf(DX[e2 * 16 + e], A[d * 25 + e2], sum);
    }
    dacc_ws[a0 * 100 + idx] = sum;
  }
}

// K3: per atom (block), per neighbor (thread): recompute geometry + embedding,
// embedding VJP -> dE -> pair -> F_self (LDS reduce) + scatter atomics.
// launch_bounds(256,2): VGPR cap 256 — ~180 live floats at peak, was spilling
// 187 MB of scratch at the default budget (VGPR_Count=84, R1 counters).
__global__ __launch_bounds__(256, 2) void k_bwd_force(
    const float* __restrict__ dR, const int* __restrict__ neigh,
    const float* __restrict__ davg, const float* __restrict__ dstd,
    const float* __restrict__ eW0, const float* __restrict__ eb0,
    const float* __restrict__ eW1, const float* __restrict__ eb1,
    const float* __restrict__ eW2, const float* __restrict__ eb2,
    const float* __restrict__ dacc_ws, float* __restrict__ out) {
  __shared__ float sF[3];
  int atom = blockIdx.x;
  int bb = atom >> 10;
  int n = atom & (N_ - 1);
  int t = (n >= 512) ? 1 : 0;
  int m = threadIdx.x;
  if (m < 3) sF[m] = 0.0f;
  __syncthreads();
  int p = __builtin_amdgcn_readfirstlane(t * 2 + (m >> 7));
  const float* W0 = eW0 + p * D_;
  const float* b0 = eb0 + p * D_;
  const float* W1 = eW1 + p * D_ * D_;
  const float* b1 = eb1 + p * D_;
  const float* W2 = eW2 + p * D_ * D_;
  const float* b2 = eb2 + p * D_;
  const float* dac = dacc_ws + atom * 100;  // block-uniform -> scalar loads
  int base = atom * M_ + m;
  float dx = dR[base * 3 + 0];
  float dy = dR[base * 3 + 1];
  float dz = dR[base * 3 + 2];
  int nb = neigh[base];
  float blk[4], rid[12];
  compute_geom<true>(dx, dy, dz, nb, t, m, davg, dstd, blk, rid);
  float h0[D_], t1v[D_], h1[D_], t2v[D_];
  embed_fwd(blk[0], W0, b0, W1, b1, W2, b2, h0, t1v, h1, t2v);
  // dblk[d] = CSC * sum_e dacc[d][e] * G[e]
  float dblk[4];
#pragma unroll
  for (int d = 0; d < 4; ++d) {
    float s = 0.0f;
#pragma unroll
    for (int e = 0; e < D_; ++e) s = fmaf(dac[d * D_ + e], h1[e] + t2v[e], s);
    dblk[d] = s * CSC;
  }
  // dG[e] = CSC * sum_d dacc[d][e] * blk[d]
  float dG[D_];
#pragma unroll
  for (int e = 0; e < D_; ++e)
    dG[e] = CSC * (dac[e] * blk[0] + dac[25 + e] * blk[1] +
                   dac[50 + e] * blk[2] + dac[75 + e] * blk[3]);
  // embedding VJP
  float g[D_];
#pragma unroll
  for (int e = 0; e < D_; ++e) g[e] = dG[e] * (1.0f - t2v[e] * t2v[e]);  // g2
#pragma unroll
  for (int e = 0; e < D_; ++e) {  // dh1 = dG + g2 @ W2^T (in place)
    float s = dG[e];
#pragma unroll
    for (int f = 0; f < D_; ++f) s = fmaf(g[f], W2[e * D_ + f], s);
    dG[e] = s;
  }
#pragma unroll
  for (int e = 0; e < D_; ++e) g[e] = dG[e] * (1.0f - t1v[e] * t1v[e]);  // g1
#pragma unroll
  for (int e = 0; e < D_; ++e) {  // dh0 = dh1 + g1 @ W1^T (in place)
    float s = dG[e];
#pragma unroll
    for (int f = 0; f < D_; ++f) s = fmaf(g[f], W1[e * D_ + f], s);
    dG[e] = s;
  }
  float ds = 0.0f;
#pragma unroll
  for (int e = 0; e < D_; ++e) ds = fmaf(dG[e] * (1.0f - h0[e] * h0[e]), W0[e], ds);
  float dE0 = dblk[0] + ds, dE1 = dblk[1], dE2 = dblk[2], dE3 = dblk[3];
  float px = dE0 * rid[0] + dE1 * rid[3] + dE2 * rid[6] + dE3 * rid[9];
  float py = dE0 * rid[1] + dE1 * rid[4] + dE2 * rid[7] + dE3 * rid[10];
  float pz = dE0 * rid[2] + dE1 * rid[5] + dE2 * rid[8] + dE3 * rid[11];
  atomicAdd(&sF[0], px);
  atomicAdd(&sF[1], py);
  atomicAdd(&sF[2], pz);
  if (nb > 0) {  // scatter to neighbor j = nb-1
    int jn = nb - 1;
    int fi = 8 + NATOM + (bb * N_ + jn) * 3;
    atomicAdd(&out[fi + 0], px);
    atomicAdd(&out[fi + 1], py);
    atomicAdd(&out[fi + 2], pz);
  }
  __syncthreads();
  if (m < 3) atomicAdd(&out[8 + NATOM + atom * 3 + m], -sF[m]);
}

}  // namespace

extern "C" void kernel_launch(void* const* d_in, const int* in_sizes, int n_in,
                              void* d_out, int out_size, void* d_ws, size_t ws_size,
                              hipStream_t stream) {
  (void)in_sizes; (void)n_in; (void)ws_size;
  const float* image_dR   = (const float*)d_in[0];
  const int*   list_neigh = (const int*)d_in[1];
  const float* davg       = (const float*)d_in[2];
  const float* dstd       = (const float*)d_in[3];
  const float* eW0        = (const float*)d_in[4];
  const float* eb0        = (const float*)d_in[5];
  const float* eW1        = (const float*)d_in[6];
  const float* eb1        = (const float*)d_in[7];
  const float* eW2        = (const float*)d_in[8];
  const float* eb2        = (const float*)d_in[9];
  const float* fW0        = (const float*)d_in[10];
  const float* fb0        = (const float*)d_in[11];
  const float* fW1        = (const float*)d_in[12];
  const float* fb1        = (const float*)d_in[13];
  const float* fW2        = (const float*)d_in[14];
  const float* fb2        = (const float*)d_in[15];
  const float* fW3        = (const float*)d_in[16];
  const float* fb3        = (const float*)d_in[17];
  const float* ener_shift = (const float*)d_in[18];
  float* out = (float*)d_out;
  float* acc_ws  = (float*)d_ws;                  // 8192*100 floats
  float* dacc_ws = acc_ws + NATOM * 100;          // 8192*100 floats

  hipMemsetAsync(d_out, 0, (size_t)out_size * sizeof(float), stream);
  k_embed_acc<<<NATOM, 256, 0, stream>>>(image_dR, list_neigh, davg, dstd,
                                         eW0, eb0, eW1, eb1, eW2, eb2, acc_ws);
  k_fit<<<NATOM / 8, 256, 0, stream>>>(acc_ws, fW0, fb0, fW1, fb1, fW2, fb2,
                                       fW3, fb3, ener_shift, dacc_ws, out);
  k_bwd_force<<<NATOM, 256, 0, stream>>>(image_dR, list_neigh, davg, dstd,
                                         eW0, eb0, eW1, eb1, eW2, eb2,
                                         dacc_ws, out);
}